// Round 1
// baseline (410.367 us; speedup 1.0000x reference)
//
#include <hip/hip_runtime.h>

#define DEVINL __device__ __forceinline__

typedef float f32x4_t __attribute__((ext_vector_type(4)));
typedef short bf16x8_t __attribute__((ext_vector_type(8)));

#define MFMA16(a, b, c) __builtin_amdgcn_mfma_f32_16x16x32_bf16((a), (b), (c), 0, 0, 0)

DEVINL unsigned short f2bf(float f) {
  union { float f; unsigned u; } v; v.f = f;
  unsigned r = v.u + 0x7fffu + ((v.u >> 16) & 1u);   // round-to-nearest-even
  return (unsigned short)(r >> 16);
}

// ---------------- kernel: convert final_w fp32 -> bf16 ----------------
__global__ __launch_bounds__(256) void kconv(const float* __restrict__ fw,
                                             unsigned short* __restrict__ wb) {
  int i = blockIdx.x * 256 + threadIdx.x;           // 32768 threads, 4 elems each
  float4 v = ((const float4*)fw)[i];
  ushort4 u;
  u.x = f2bf(v.x); u.y = f2bf(v.y); u.z = f2bf(v.z); u.w = f2bf(v.w);
  ((ushort4*)wb)[i] = u;
}

// ---------------- kernel A: LayerNorm + proj + split, write I/J bf16 ----------------
// I layout: Ig[(l*32 + x)*128 + m]  (i scaled by 1/128, exact in bf16)
// J layout: Jg[(l*32 + y)*128 + m]
__global__ __launch_bounds__(256) void kA(const float* __restrict__ x,
                                          const float* __restrict__ nw,
                                          const float* __restrict__ nb,
                                          const float* __restrict__ pw,
                                          const float* __restrict__ pb,
                                          unsigned short* __restrict__ Ig,
                                          unsigned short* __restrict__ Jg) {
  __shared__ unsigned short xnl[32 * 264];   // 32 rows x 256 (+8 pad) bf16
  __shared__ unsigned short pwl[64 * 264];   // 64 d   x 256 (+8 pad) bf16
  const int tid  = threadIdx.x;
  const int wv   = tid >> 6;
  const int lane = tid & 63;
  const int q    = lane >> 4;
  const int ln16 = lane & 15;
  const int rl0  = blockIdx.x * 32;          // 32 rows (m,l) per block

  // coalesced load: iter i covers rows 4i..4i+3; wave wv ends up owning row 4i+wv,
  // lane holds channels 4*lane..4*lane+3 of that row.
  const float4* xs = (const float4*)(x + rl0 * 256);
  float4 v[8];
#pragma unroll
  for (int i = 0; i < 8; i++) v[i] = xs[i * 256 + tid];
  float4 nw4 = ((const float4*)nw)[lane];
  float4 nb4 = ((const float4*)nb)[lane];

#pragma unroll
  for (int i = 0; i < 8; i++) {
    float s  = v[i].x + v[i].y + v[i].z + v[i].w;
    float ss = v[i].x * v[i].x + v[i].y * v[i].y + v[i].z * v[i].z + v[i].w * v[i].w;
#pragma unroll
    for (int off = 32; off > 0; off >>= 1) {
      s  += __shfl_xor(s, off);
      ss += __shfl_xor(ss, off);
    }
    float mu  = s * (1.0f / 256.0f);
    float var = ss * (1.0f / 256.0f) - mu * mu;
    float rs  = rsqrtf(var + 1e-5f);
    ushort4 u;
    u.x = f2bf((v[i].x - mu) * rs * nw4.x + nb4.x);
    u.y = f2bf((v[i].y - mu) * rs * nw4.y + nb4.y);
    u.z = f2bf((v[i].z - mu) * rs * nw4.z + nb4.z);
    u.w = f2bf((v[i].w - mu) * rs * nw4.w + nb4.w);
    int row = i * 4 + wv;
    *(ushort4*)&xnl[row * 264 + lane * 4] = u;
  }

  // stage proj_w (64 x 256 fp32) -> bf16 LDS
  const float4* ps = (const float4*)pw;
#pragma unroll
  for (int i = 0; i < 16; i++) {
    float4 w4 = ps[i * 256 + tid];
    ushort4 u;
    u.x = f2bf(w4.x); u.y = f2bf(w4.y); u.z = f2bf(w4.z); u.w = f2bf(w4.w);
    int d = i * 4 + wv;
    *(ushort4*)&pwl[d * 264 + lane * 4] = u;
  }
  __syncthreads();

  // MFMA: rows (32) x d (64), K = 256. wave -> row-tile (wv&1), d-tiles (wv>>1)*32..+31
  const int rt = wv & 1;
  const int db = (wv >> 1) * 32;
  f32x4_t acc[2] = {{0.f, 0.f, 0.f, 0.f}, {0.f, 0.f, 0.f, 0.f}};
#pragma unroll
  for (int kc = 0; kc < 8; kc++) {
    bf16x8_t a  = *(const bf16x8_t*)&xnl[(rt * 16 + ln16) * 264 + kc * 32 + q * 8];
    bf16x8_t b0 = *(const bf16x8_t*)&pwl[(db + ln16) * 264 + kc * 32 + q * 8];
    bf16x8_t b1 = *(const bf16x8_t*)&pwl[(db + 16 + ln16) * 264 + kc * 32 + q * 8];
    acc[0] = MFMA16(a, b0, acc[0]);
    acc[1] = MFMA16(a, b1, acc[1]);
  }

  // epilogue: D[row=(q*4+r)][col=ln16]; scatter bf16 to Ig/Jg (K-major for stage B)
#pragma unroll
  for (int t2 = 0; t2 < 2; t2++) {
    int d = db + t2 * 16 + ln16;
    float bias = pb[d];
    int half = d >> 1;
    unsigned short* dst = (d & 1) ? Jg : Ig;
    float scale = (d & 1) ? 1.0f : (1.0f / 128.0f);
#pragma unroll
    for (int r = 0; r < 4; r++) {
      int rl = rl0 + rt * 16 + q * 4 + r;
      int l = rl & 255;
      int m = rl >> 8;
      dst[(l * 32 + half) * 128 + m] = f2bf((acc[t2][r] + bias) * scale);
    }
  }
}

// ---------------- kernel B: fused outer-product-mean + final GEMM ----------------
// block = (il, jl-block of 32); GEMM1 builds flat[32][1024] bf16 in LDS, GEMM2
// streams W bf16 (f-chunks of 128) and accumulates out[32][128] fp32.
__global__ __launch_bounds__(256) void kB(const unsigned short* __restrict__ Ig,
                                          const unsigned short* __restrict__ Jg,
                                          const unsigned short* __restrict__ Wb,
                                          const float* __restrict__ fb,
                                          float* __restrict__ out) {
  extern __shared__ unsigned short sm[];
  unsigned short* i_t = sm;                        // 32*136  = 4352 us
  unsigned short* j_t = sm + 4352;                 // 64*136  = 8704 us
  unsigned short* w_t = sm + 4352 + 8704;          // 128*136 = 17408 us
  unsigned short* fl  = sm + 4352 + 8704 + 17408;  // 32*1032 = 33024 us
  const int tid  = threadIdx.x;
  const int wv   = tid >> 6;
  const int lane = tid & 63;
  const int q    = lane >> 4;
  const int ln16 = lane & 15;
  const int il   = blockIdx.x >> 3;
  const int jl0  = (blockIdx.x & 7) * 32;

  // stage i_t: I_il (32 x-rows x 128 m) bf16
  {
    const ushort4* src = (const ushort4*)(Ig + il * 4096);
#pragma unroll
    for (int c = tid; c < 2048; c += 256) {
      int e = c * 4, row = e >> 7, col = e & 127;
      *(ushort4*)&i_t[row * 136 + col] = src[c];
    }
  }

  // ---- GEMM1: 16 chunks of 2 jl; out chunk = 32 x-rows x 64 jy-cols, K=128 (m) ----
  for (int ch = 0; ch < 16; ch++) {
    __syncthreads();   // protect j_t from previous chunk's readers
    const ushort4* src = (const ushort4*)(Jg + (jl0 + ch * 2) * 4096);
#pragma unroll
    for (int c = tid; c < 2048; c += 256) {
      int e = c * 4, row = e >> 7, col = e & 127;
      *(ushort4*)&j_t[row * 136 + col] = src[c];
    }
    __syncthreads();
    const int xt = (wv & 1) * 16;
    const int jb = (wv >> 1) * 32;
    f32x4_t g[2] = {{0.f, 0.f, 0.f, 0.f}, {0.f, 0.f, 0.f, 0.f}};
#pragma unroll
    for (int kc = 0; kc < 4; kc++) {
      bf16x8_t a  = *(const bf16x8_t*)&i_t[(xt + ln16) * 136 + kc * 32 + q * 8];
      bf16x8_t b0 = *(const bf16x8_t*)&j_t[(jb + ln16) * 136 + kc * 32 + q * 8];
      bf16x8_t b1 = *(const bf16x8_t*)&j_t[(jb + 16 + ln16) * 136 + kc * 32 + q * 8];
      g[0] = MFMA16(a, b0, g[0]);
      g[1] = MFMA16(a, b1, g[1]);
    }
    // write flat rows (bf16): flat[jl_local][x*32+y]
#pragma unroll
    for (int t2 = 0; t2 < 2; t2++) {
      int jy = jb + t2 * 16 + ln16;
      int fr = ch * 2 + (jy >> 5);
      int y  = jy & 31;
#pragma unroll
      for (int r = 0; r < 4; r++) {
        int xx = xt + q * 4 + r;
        fl[fr * 1032 + xx * 32 + y] = f2bf(g[t2][r]);
      }
    }
  }

  // ---- GEMM2: out[32 jl][128 o] = flat[32][1024] @ W^T, stream W in 8 f-chunks ----
  f32x4_t o2[2][2] = {{{0.f, 0.f, 0.f, 0.f}, {0.f, 0.f, 0.f, 0.f}},
                      {{0.f, 0.f, 0.f, 0.f}, {0.f, 0.f, 0.f, 0.f}}};
  const ushort4* wsrc = (const ushort4*)Wb;
  for (int fc = 0; fc < 8; fc++) {
    __syncthreads();   // flat ready (fc=0) / w_t readers done (fc>0)
#pragma unroll
    for (int c = tid; c < 4096; c += 256) {
      int o = c >> 5, col4 = c & 31;
      *(ushort4*)&w_t[o * 136 + col4 * 4] = wsrc[o * 256 + fc * 32 + col4];
    }
    __syncthreads();
#pragma unroll
    for (int kc = 0; kc < 4; kc++) {
      int f = fc * 128 + kc * 32 + q * 8;
      bf16x8_t a0 = *(const bf16x8_t*)&fl[ln16 * 1032 + f];
      bf16x8_t a1 = *(const bf16x8_t*)&fl[(16 + ln16) * 1032 + f];
      bf16x8_t b0 = *(const bf16x8_t*)&w_t[(wv * 32 + ln16) * 136 + kc * 32 + q * 8];
      bf16x8_t b1 = *(const bf16x8_t*)&w_t[(wv * 32 + 16 + ln16) * 136 + kc * 32 + q * 8];
      o2[0][0] = MFMA16(a0, b0, o2[0][0]);
      o2[0][1] = MFMA16(a0, b1, o2[0][1]);
      o2[1][0] = MFMA16(a1, b0, o2[1][0]);
      o2[1][1] = MFMA16(a1, b1, o2[1][1]);
    }
  }

  float* op = out + (il * 256 + jl0) * 128;
#pragma unroll
  for (int rt = 0; rt < 2; rt++) {
#pragma unroll
    for (int ot = 0; ot < 2; ot++) {
      int o = wv * 32 + ot * 16 + ln16;
      float bias = fb[o];
#pragma unroll
      for (int r = 0; r < 4; r++) {
        int row = rt * 16 + q * 4 + r;
        op[row * 128 + o] = o2[rt][ot][r] + bias;
      }
    }
  }
}

extern "C" void kernel_launch(void* const* d_in, const int* in_sizes, int n_in,
                              void* d_out, int out_size, void* d_ws, size_t ws_size,
                              hipStream_t stream) {
  const float* x1d     = (const float*)d_in[0];
  const float* norm_w  = (const float*)d_in[1];
  const float* norm_b  = (const float*)d_in[2];
  const float* proj_w  = (const float*)d_in[3];
  const float* proj_b  = (const float*)d_in[4];
  const float* final_w = (const float*)d_in[5];
  const float* final_b = (const float*)d_in[6];
  float* outp          = (float*)d_out;

  // workspace carve (bf16): W (128*1024), I (256*32*128), J (256*32*128)
  unsigned short* Wb = (unsigned short*)d_ws;
  unsigned short* Igp = Wb + 131072;
  unsigned short* Jgp = Igp + 1048576;

  const int kb_lds = (4352 + 8704 + 17408 + 33024) * 2;   // 126976 B
  hipFuncSetAttribute((const void*)kB, hipFuncAttributeMaxDynamicSharedMemorySize, kb_lds);

  kconv<<<128, 256, 0, stream>>>(final_w, Wb);
  kA<<<1024, 256, 0, stream>>>(x1d, norm_w, norm_b, proj_w, proj_b, Igp, Jgp);
  kB<<<2048, 256, kb_lds, stream>>>(Igp, Jgp, Wb, final_b, outp);
}

// Round 2
// 218.069 us; speedup vs baseline: 1.8818x; 1.8818x over previous
//
#include <hip/hip_runtime.h>

#define DEVINL __device__ __forceinline__

typedef float f32x4_t __attribute__((ext_vector_type(4)));
typedef short bf16x8_t __attribute__((ext_vector_type(8)));

#define MFMA16(a, b, c) __builtin_amdgcn_mfma_f32_16x16x32_bf16((a), (b), (c), 0, 0, 0)

DEVINL unsigned short f2bf(float f) {
  union { float f; unsigned u; } v; v.f = f;
  unsigned r = v.u + 0x7fffu + ((v.u >> 16) & 1u);   // round-to-nearest-even
  return (unsigned short)(r >> 16);
}

// ---------------- kernel A: LayerNorm + proj + split (+ final_w conversion) --------
// Block bid<1024: (l = bid&255, m0 = (bid>>8)*32): 32 rows (m0..m0+31, fixed l).
// Outputs K-major bf16:  Ig[(l*32 + x)*128 + m]  (scaled 1/128),  Jg likewise.
// Blocks 1024..1151: convert final_w fp32 -> bf16 into Wb.
__global__ __launch_bounds__(256) void kA(const float* __restrict__ x,
                                          const float* __restrict__ nw,
                                          const float* __restrict__ nb,
                                          const float* __restrict__ pw,
                                          const float* __restrict__ pb,
                                          const float* __restrict__ fw,
                                          unsigned short* __restrict__ Wb,
                                          unsigned short* __restrict__ Ig,
                                          unsigned short* __restrict__ Jg) {
  if (blockIdx.x >= 1024) {                  // final_w fp32 -> bf16 (128 blocks)
    int i = (blockIdx.x - 1024) * 256 + threadIdx.x;
    float4 v = ((const float4*)fw)[i];
    ushort4 u;
    u.x = f2bf(v.x); u.y = f2bf(v.y); u.z = f2bf(v.z); u.w = f2bf(v.w);
    ((ushort4*)Wb)[i] = u;
    return;
  }
  __shared__ unsigned short xnl[32 * 264];   // 32 m-rows x 256 ch (+8 pad)
  __shared__ unsigned short pwl[64 * 264];   // 64 d x 256 ch (+8 pad)
  __shared__ unsigned short ep[64 * 36];     // transpose buf: [d][m-local]
  const int tid  = threadIdx.x;
  const int wv   = tid >> 6;
  const int lane = tid & 63;
  const int q    = lane >> 4;
  const int ln16 = lane & 15;
  const int l    = blockIdx.x & 255;
  const int m0   = (blockIdx.x >> 8) * 32;

  // load 32 rows (m0+4i+wv, l): wave owns whole rows, lane = 4 channels. 1KB bursts.
  const float4* xs = (const float4*)x;
  float4 v[8];
#pragma unroll
  for (int i = 0; i < 8; i++) {
    int row = m0 + i * 4 + wv;
    v[i] = xs[row * 16384 + l * 64 + lane];
  }
  float4 nw4 = ((const float4*)nw)[lane];
  float4 nb4 = ((const float4*)nb)[lane];

#pragma unroll
  for (int i = 0; i < 8; i++) {
    float s  = v[i].x + v[i].y + v[i].z + v[i].w;
    float ss = v[i].x * v[i].x + v[i].y * v[i].y + v[i].z * v[i].z + v[i].w * v[i].w;
#pragma unroll
    for (int off = 32; off > 0; off >>= 1) {
      s  += __shfl_xor(s, off);
      ss += __shfl_xor(ss, off);
    }
    float mu  = s * (1.0f / 256.0f);
    float var = ss * (1.0f / 256.0f) - mu * mu;
    float rs  = rsqrtf(var + 1e-5f);
    ushort4 u;
    u.x = f2bf((v[i].x - mu) * rs * nw4.x + nb4.x);
    u.y = f2bf((v[i].y - mu) * rs * nw4.y + nb4.y);
    u.z = f2bf((v[i].z - mu) * rs * nw4.z + nb4.z);
    u.w = f2bf((v[i].w - mu) * rs * nw4.w + nb4.w);
    *(ushort4*)&xnl[(i * 4 + wv) * 264 + lane * 4] = u;
  }

  // stage proj_w (64 x 256 fp32) -> bf16 LDS
  const float4* ps = (const float4*)pw;
#pragma unroll
  for (int i = 0; i < 16; i++) {
    float4 w4 = ps[i * 256 + tid];
    ushort4 u;
    u.x = f2bf(w4.x); u.y = f2bf(w4.y); u.z = f2bf(w4.z); u.w = f2bf(w4.w);
    *(ushort4*)&pwl[(i * 4 + wv) * 264 + lane * 4] = u;
  }
  __syncthreads();

  // MFMA: 32 m-rows x 64 d, K=256. wave -> m-tile (wv&1), d-block (wv>>1)*32
  const int rt = wv & 1;
  const int db = (wv >> 1) * 32;
  f32x4_t acc[2] = {{0.f, 0.f, 0.f, 0.f}, {0.f, 0.f, 0.f, 0.f}};
#pragma unroll
  for (int kc = 0; kc < 8; kc++) {
    bf16x8_t a  = *(const bf16x8_t*)&xnl[(rt * 16 + ln16) * 264 + kc * 32 + q * 8];
    bf16x8_t b0 = *(const bf16x8_t*)&pwl[(db + ln16) * 264 + kc * 32 + q * 8];
    bf16x8_t b1 = *(const bf16x8_t*)&pwl[(db + 16 + ln16) * 264 + kc * 32 + q * 8];
    acc[0] = MFMA16(a, b0, acc[0]);
    acc[1] = MFMA16(a, b1, acc[1]);
  }

  // epilogue: lane holds D[m=rt*16+q*4+r][d=db+t2*16+ln16]; transpose via ep LDS
#pragma unroll
  for (int t2 = 0; t2 < 2; t2++) {
    int d = db + t2 * 16 + ln16;
    float bias  = pb[d];
    float scale = (d & 1) ? 1.0f : (1.0f / 128.0f);
#pragma unroll
    for (int r = 0; r < 4; r++) {
      int mloc = rt * 16 + q * 4 + r;
      ep[d * 36 + mloc] = f2bf((acc[t2][r] + bias) * scale);
    }
  }
  __syncthreads();

  // coalesced stores: I from even d, J from odd d. 64-B runs per half-channel.
  const int h  = tid >> 3;
  const int m4 = tid & 7;
  ushort4 vi = *(const ushort4*)&ep[(2 * h) * 36 + m4 * 4];
  *(ushort4*)&Ig[(l * 32 + h) * 128 + m0 + m4 * 4] = vi;
  ushort4 vj = *(const ushort4*)&ep[(2 * h + 1) * 36 + m4 * 4];
  *(ushort4*)&Jg[(l * 32 + h) * 128 + m0 + m4 * 4] = vj;
}

// ---------------- kernel B: fused outer-product-mean + final GEMM ----------------
// Block = (il, 32 jl). GEMM1 reads I/J frags DIRECT from L2 (K-major, 16B/lane),
// builds fl[32 jl][1024 f] bf16 in LDS; ONE barrier; GEMM2 streams W frags direct
// from L2 and accumulates out[32][128] fp32. LDS 66 KB -> 2 blocks/CU.
__global__ __launch_bounds__(256) void kB(const unsigned short* __restrict__ Ig,
                                          const unsigned short* __restrict__ Jg,
                                          const unsigned short* __restrict__ Wb,
                                          const float* __restrict__ fb,
                                          float* __restrict__ out) {
  extern __shared__ unsigned short fl[];     // 32 x 1032 (pitch pad 8)
  const int tid  = threadIdx.x;
  const int wv   = tid >> 6;
  const int lane = tid & 63;
  const int q    = lane >> 4;
  const int ln16 = lane & 15;
  const int il   = blockIdx.x >> 3;
  const int jl0  = (blockIdx.x & 7) * 32;

  // ---- GEMM1: P[x(32)][jy(1024)] = I_il (32x128) @ J_block^T, K=128 (m) ----
  // A-frags (I) held in registers; wave owns disjoint jy range [wv*256, wv*256+256)
  const unsigned short* Ibase = Ig + il * 4096;
  bf16x8_t af[2][4];
#pragma unroll
  for (int xt = 0; xt < 2; xt++)
#pragma unroll
    for (int kc = 0; kc < 4; kc++)
      af[xt][kc] = *(const bf16x8_t*)&Ibase[(xt * 16 + ln16) * 128 + kc * 32 + q * 8];

  const unsigned short* Jbase = Jg + ((blockIdx.x & 7) * 1024 + wv * 256) * 128;
#pragma unroll
  for (int jp = 0; jp < 8; jp++) {           // 2 jy-tiles per iter
    bf16x8_t bf[2][4];
#pragma unroll
    for (int u = 0; u < 2; u++)
#pragma unroll
      for (int kc = 0; kc < 4; kc++)
        bf[u][kc] = *(const bf16x8_t*)&Jbase[((jp * 2 + u) * 16 + ln16) * 128 + kc * 32 + q * 8];
    f32x4_t ac[2][2] = {{{0.f,0.f,0.f,0.f},{0.f,0.f,0.f,0.f}},
                        {{0.f,0.f,0.f,0.f},{0.f,0.f,0.f,0.f}}};
#pragma unroll
    for (int kc = 0; kc < 4; kc++) {
#pragma unroll
      for (int u = 0; u < 2; u++) {
        ac[u][0] = MFMA16(af[0][kc], bf[u][kc], ac[u][0]);
        ac[u][1] = MFMA16(af[1][kc], bf[u][kc], ac[u][1]);
      }
    }
    // lane holds P[x = xt*16+q*4+r][jy = tile+ln16]; write fl[jl_loc][x*32+y]
#pragma unroll
    for (int u = 0; u < 2; u++) {
      int jyl = wv * 256 + (jp * 2 + u) * 16 + ln16;   // block-local jy
      int fr  = jyl >> 5;
      int y   = jyl & 31;
#pragma unroll
      for (int xt = 0; xt < 2; xt++)
#pragma unroll
        for (int r = 0; r < 4; r++)
          fl[fr * 1032 + (xt * 16 + q * 4 + r) * 32 + y] = f2bf(ac[u][xt][r]);
    }
  }
  __syncthreads();                            // the ONLY barrier

  // ---- GEMM2: out[32 jl][128 o] = fl @ W^T, K=1024; W frags direct from L2 ----
  f32x4_t o2[2][2] = {{{0.f,0.f,0.f,0.f},{0.f,0.f,0.f,0.f}},
                      {{0.f,0.f,0.f,0.f},{0.f,0.f,0.f,0.f}}};
#pragma unroll 4
  for (int kc = 0; kc < 32; kc++) {
    bf16x8_t a0 = *(const bf16x8_t*)&fl[ln16 * 1032 + kc * 32 + q * 8];
    bf16x8_t a1 = *(const bf16x8_t*)&fl[(16 + ln16) * 1032 + kc * 32 + q * 8];
    bf16x8_t b0 = *(const bf16x8_t*)&Wb[(wv * 32 + ln16) * 1024 + kc * 32 + q * 8];
    bf16x8_t b1 = *(const bf16x8_t*)&Wb[(wv * 32 + 16 + ln16) * 1024 + kc * 32 + q * 8];
    o2[0][0] = MFMA16(a0, b0, o2[0][0]);
    o2[0][1] = MFMA16(a0, b1, o2[0][1]);
    o2[1][0] = MFMA16(a1, b0, o2[1][0]);
    o2[1][1] = MFMA16(a1, b1, o2[1][1]);
  }

  float* op = out + (il * 256 + jl0) * 128;
#pragma unroll
  for (int rtt = 0; rtt < 2; rtt++) {
#pragma unroll
    for (int ot = 0; ot < 2; ot++) {
      int o = wv * 32 + ot * 16 + ln16;
      float bias = fb[o];
#pragma unroll
      for (int r = 0; r < 4; r++) {
        int row = rtt * 16 + q * 4 + r;
        op[row * 128 + o] = o2[rtt][ot][r] + bias;
      }
    }
  }
}

extern "C" void kernel_launch(void* const* d_in, const int* in_sizes, int n_in,
                              void* d_out, int out_size, void* d_ws, size_t ws_size,
                              hipStream_t stream) {
  const float* x1d     = (const float*)d_in[0];
  const float* norm_w  = (const float*)d_in[1];
  const float* norm_b  = (const float*)d_in[2];
  const float* proj_w  = (const float*)d_in[3];
  const float* proj_b  = (const float*)d_in[4];
  const float* final_w = (const float*)d_in[5];
  const float* final_b = (const float*)d_in[6];
  float* outp          = (float*)d_out;

  // workspace carve (bf16): W (128*1024), I (256*32*128), J (256*32*128)
  unsigned short* Wb  = (unsigned short*)d_ws;
  unsigned short* Igp = Wb + 131072;
  unsigned short* Jgp = Igp + 1048576;

  const int kb_lds = 32 * 1032 * 2;   // 66048 B
  hipFuncSetAttribute((const void*)kB, hipFuncAttributeMaxDynamicSharedMemorySize, kb_lds);

  kA<<<1152, 256, 0, stream>>>(x1d, norm_w, norm_b, proj_w, proj_b, final_w, Wb, Igp, Jgp);
  kB<<<2048, 256, kb_lds, stream>>>(Igp, Jgp, Wb, final_b, outp);
}

// Round 3
// 142.316 us; speedup vs baseline: 2.8835x; 1.5323x over previous
//
#include <hip/hip_runtime.h>

#define DEVINL __device__ __forceinline__

typedef float  f32x4_t  __attribute__((ext_vector_type(4)));
typedef float  f32x16_t __attribute__((ext_vector_type(16)));
typedef short  bf16x8_t __attribute__((ext_vector_type(8)));

#define MFMA16(a,b,c) __builtin_amdgcn_mfma_f32_16x16x32_bf16((a),(b),(c),0,0,0)
#define MFMA32(a,b,c) __builtin_amdgcn_mfma_f32_32x32x16_bf16((a),(b),(c),0,0,0)

DEVINL unsigned short f2bf(float f) {
  union { float f; unsigned u; } v; v.f = f;
  unsigned r = v.u + 0x7fffu + ((v.u >> 16) & 1u);   // round-to-nearest-even
  return (unsigned short)(r >> 16);
}

// ============================ fragment-order layouts ============================
// I/J (bf16): idx = (rowtile*8 + mc)*512 + r32*16 + h*8 + e
//   rowtile = (global row)>>5 (I rows: il*32+x; J rows: jl*32+y), r32 = row&31,
//   m = mc*16 + h*8 + e.  A/B frag for 32x32x16 = 16B at (r32=lane&31, h=lane>>5).
// W (bf16):  idx = (ot*64 + kc)*512 + o32*16 + h*8 + e;  o = ot*32+o32, f = kc*16+h*8+e.

// ---------------- kernel A: LayerNorm + proj + split (+ final_w conversion) ------
__global__ __launch_bounds__(256) void kA(const float* __restrict__ x,
                                          const float* __restrict__ nw,
                                          const float* __restrict__ nb,
                                          const float* __restrict__ pw,
                                          const float* __restrict__ pb,
                                          const float* __restrict__ fw,
                                          unsigned short* __restrict__ Wb,
                                          unsigned short* __restrict__ Ig,
                                          unsigned short* __restrict__ Jg) {
  if (blockIdx.x >= 1024) {                  // final_w fp32 -> bf16, frag order
    int i = (blockIdx.x - 1024) * 256 + threadIdx.x;   // 0..32767
    float4 v = ((const float4*)fw)[i];
    int o  = i >> 8;
    int f0 = (i & 255) * 4;
    ushort4 u;
    u.x = f2bf(v.x); u.y = f2bf(v.y); u.z = f2bf(v.z); u.w = f2bf(v.w);
    size_t off = (size_t)((o >> 5) * 64 + (f0 >> 4)) * 512 + (o & 31) * 16 + ((f0 >> 3) & 1) * 8 + (f0 & 7);
    *(ushort4*)&Wb[off] = u;
    return;
  }
  __shared__ unsigned short xnl[32 * 264];   // 32 m-rows x 256 ch (+8 pad)
  __shared__ unsigned short pwl[64 * 264];   // 64 d x 256 ch (+8 pad)
  __shared__ unsigned short ep[64 * 36];     // transpose buf: [d][m-local]
  const int tid  = threadIdx.x;
  const int wv   = tid >> 6;
  const int lane = tid & 63;
  const int q    = lane >> 4;
  const int ln16 = lane & 15;
  const int l    = blockIdx.x & 255;
  const int m0   = (blockIdx.x >> 8) * 32;

  const float4* xs = (const float4*)x;
  float4 v[8];
#pragma unroll
  for (int i = 0; i < 8; i++) {
    int row = m0 + i * 4 + wv;
    v[i] = xs[row * 16384 + l * 64 + lane];
  }
  float4 nw4 = ((const float4*)nw)[lane];
  float4 nb4 = ((const float4*)nb)[lane];

#pragma unroll
  for (int i = 0; i < 8; i++) {
    float s  = v[i].x + v[i].y + v[i].z + v[i].w;
    float ss = v[i].x * v[i].x + v[i].y * v[i].y + v[i].z * v[i].z + v[i].w * v[i].w;
#pragma unroll
    for (int off = 32; off > 0; off >>= 1) {
      s  += __shfl_xor(s, off);
      ss += __shfl_xor(ss, off);
    }
    float mu  = s * (1.0f / 256.0f);
    float var = ss * (1.0f / 256.0f) - mu * mu;
    float rs  = rsqrtf(var + 1e-5f);
    ushort4 u;
    u.x = f2bf((v[i].x - mu) * rs * nw4.x + nb4.x);
    u.y = f2bf((v[i].y - mu) * rs * nw4.y + nb4.y);
    u.z = f2bf((v[i].z - mu) * rs * nw4.z + nb4.z);
    u.w = f2bf((v[i].w - mu) * rs * nw4.w + nb4.w);
    *(ushort4*)&xnl[(i * 4 + wv) * 264 + lane * 4] = u;
  }

  const float4* ps = (const float4*)pw;
#pragma unroll
  for (int i = 0; i < 16; i++) {
    float4 w4 = ps[i * 256 + tid];
    ushort4 u;
    u.x = f2bf(w4.x); u.y = f2bf(w4.y); u.z = f2bf(w4.z); u.w = f2bf(w4.w);
    *(ushort4*)&pwl[(i * 4 + wv) * 264 + lane * 4] = u;
  }
  __syncthreads();

  const int rt = wv & 1;
  const int db = (wv >> 1) * 32;
  f32x4_t acc[2] = {{0.f, 0.f, 0.f, 0.f}, {0.f, 0.f, 0.f, 0.f}};
#pragma unroll
  for (int kc = 0; kc < 8; kc++) {
    bf16x8_t a  = *(const bf16x8_t*)&xnl[(rt * 16 + ln16) * 264 + kc * 32 + q * 8];
    bf16x8_t b0 = *(const bf16x8_t*)&pwl[(db + ln16) * 264 + kc * 32 + q * 8];
    bf16x8_t b1 = *(const bf16x8_t*)&pwl[(db + 16 + ln16) * 264 + kc * 32 + q * 8];
    acc[0] = MFMA16(a, b0, acc[0]);
    acc[1] = MFMA16(a, b1, acc[1]);
  }

#pragma unroll
  for (int t2 = 0; t2 < 2; t2++) {
    int d = db + t2 * 16 + ln16;
    float bias  = pb[d];
    float scale = (d & 1) ? 1.0f : (1.0f / 128.0f);
#pragma unroll
    for (int r = 0; r < 4; r++) {
      int mloc = rt * 16 + q * 4 + r;
      ep[d * 36 + mloc] = f2bf((acc[t2][r] + bias) * scale);
    }
  }
  __syncthreads();

  // frag-order stores: I from even d (h row), J from odd d.
  const int h  = tid >> 3;          // 0..31 (x or y)
  const int m4 = tid & 7;           // m = m0 + m4*4
  const size_t off = (size_t)(l * 8 + (m0 >> 4) + (m4 >> 2)) * 512 + h * 16 + ((m4 >> 1) & 1) * 8 + (m4 & 1) * 4;
  ushort4 vi = *(const ushort4*)&ep[(2 * h) * 36 + m4 * 4];
  *(ushort4*)&Ig[off] = vi;
  ushort4 vj = *(const ushort4*)&ep[(2 * h + 1) * 36 + m4 * 4];
  *(ushort4*)&Jg[off] = vj;
}

// ---------------- kernel B: fused outer-product-mean + final GEMM ----------------
// 1024 blocks x 512 thr. Block: il-pair p = bid>>3, jl-tile t = bid&7 (32 jl).
// GEMM1: P[x][jy] via 32x32x16 MFMA, J frags 1KB coalesced, fl in LDS (XOR-swizzled).
// One barrier. GEMM2: out[2il][32 jl][128 o] via 32x32x16, W frags 1KB coalesced.
__global__ __launch_bounds__(512, 2) void kB(const unsigned short* __restrict__ Ig,
                                             const unsigned short* __restrict__ Jg,
                                             const unsigned short* __restrict__ Wb,
                                             const float* __restrict__ fb,
                                             float* __restrict__ out) {
  extern __shared__ unsigned short fl[];     // [2 il][32 jl][1032] (pitch pad 8)
  const int tid  = threadIdx.x;
  const int w    = tid >> 6;                 // wave 0..7
  const int lane = tid & 63;
  const int ln32 = lane & 31;
  const int h    = lane >> 5;                // k-octet half
  const int p    = blockIdx.x >> 3;          // il-pair
  const int t    = blockIdx.x & 7;           // jl-tile

  // ---- A-frags (I) for both il, held in registers (16 x b128) ----
  bf16x8_t af[2][8];
#pragma unroll
  for (int il = 0; il < 2; il++)
#pragma unroll
    for (int mc = 0; mc < 8; mc++)
      af[il][mc] = *(const bf16x8_t*)&Ig[(size_t)((p * 2 + il) * 8 + mc) * 512 + ln32 * 16 + h * 8];

  // ---- GEMM1: wave w covers jy-local [w*128, w*128+128) = 4 subtiles of 32 ----
  const unsigned short* Jbase = Jg + (size_t)(t * 32 + w * 4) * 4096 + ln32 * 16 + h * 8;
  const int eo = ln32 & 7;                   // elem within octet
  const int oc = ln32 >> 3;                  // y-octet

  bf16x8_t bf[2][8];
#pragma unroll
  for (int mc = 0; mc < 8; mc++) bf[0][mc] = *(const bf16x8_t*)&Jbase[mc * 512];

#pragma unroll
  for (int s = 0; s < 4; s++) {
    if (s < 3) {
#pragma unroll
      for (int mc = 0; mc < 8; mc++)
        bf[(s + 1) & 1][mc] = *(const bf16x8_t*)&Jbase[(s + 1) * 4096 + mc * 512];
    }
    f32x16_t a0, a1;
#pragma unroll
    for (int i = 0; i < 16; i++) { a0[i] = 0.f; a1[i] = 0.f; }
#pragma unroll
    for (int mc = 0; mc < 8; mc++) {
      a0 = MFMA32(af[0][mc], bf[s & 1][mc], a0);
      a1 = MFMA32(af[1][mc], bf[s & 1][mc], a1);
    }
    // write P -> fl, XOR chunk swizzle: c' = (x*4 + oc) ^ (5*((x>>2)&3))
    const int fr = w * 4 + s;                // jl row
    unsigned short* fr0 = &fl[fr * 1032 + eo];
#pragma unroll
    for (int reg = 0; reg < 16; reg++) {
      int xx  = (reg & 3) + 8 * (reg >> 2) + 4 * h;
      int cp  = ((xx * 4 + oc) ^ (((xx >> 2) & 3) * 5)) * 8;
      fr0[cp]         = f2bf(a0[reg]);
      fr0[33024 + cp] = f2bf(a1[reg]);
    }
  }
  __syncthreads();                           // the ONLY barrier

  // ---- GEMM2: wave w -> il = w>>2, o-tile ot = w&3; K = 1024 in 64 steps ----
  const int il = w >> 2;
  const int ot = w & 3;
  const unsigned short* Wp  = Wb + (size_t)(ot * 64) * 512 + ln32 * 16 + h * 8;
  const unsigned short* flp = fl + il * 33024 + ln32 * 1032;

  f32x16_t oa;
#pragma unroll
  for (int i = 0; i < 16; i++) oa[i] = 0.f;

#define LDA(kc) (*(const bf16x8_t*)&flp[((((kc) >> 1) * 4 + ((kc) & 1) * 2 + h) ^ ((((kc) >> 3) & 3) * 5)) * 8])
  bf16x8_t a0 = LDA(0);
  bf16x8_t b0 = *(const bf16x8_t*)&Wp[0];
  bf16x8_t b1 = *(const bf16x8_t*)&Wp[512];
#pragma unroll 8
  for (int kc = 0; kc < 64; kc++) {
    bf16x8_t an = a0, bn = b1;
    if (kc < 63) an = LDA(kc + 1);
    if (kc < 62) bn = *(const bf16x8_t*)&Wp[(kc + 2) * 512];
    oa = MFMA32(a0, b0, oa);
    a0 = an; b0 = b1; b1 = bn;
  }
#undef LDA

  // epilogue: D[row=jl][col=o]; rows (reg&3)+8*(reg>>2)+4*h, col ln32
  float bias = fb[ot * 32 + ln32];
  float* op = out + ((size_t)(p * 2 + il) * 256 + t * 32) * 128 + ot * 32 + ln32;
#pragma unroll
  for (int reg = 0; reg < 16; reg++) {
    int row = (reg & 3) + 8 * (reg >> 2) + 4 * h;
    op[row * 128] = oa[reg] + bias;
  }
}

extern "C" void kernel_launch(void* const* d_in, const int* in_sizes, int n_in,
                              void* d_out, int out_size, void* d_ws, size_t ws_size,
                              hipStream_t stream) {
  const float* x1d     = (const float*)d_in[0];
  const float* norm_w  = (const float*)d_in[1];
  const float* norm_b  = (const float*)d_in[2];
  const float* proj_w  = (const float*)d_in[3];
  const float* proj_b  = (const float*)d_in[4];
  const float* final_w = (const float*)d_in[5];
  const float* final_b = (const float*)d_in[6];
  float* outp          = (float*)d_out;

  // workspace carve (bf16): W (128*1024), I (256*32*128), J (256*32*128)
  unsigned short* Wb  = (unsigned short*)d_ws;
  unsigned short* Igp = Wb + 131072;
  unsigned short* Jgp = Igp + 1048576;

  const int kb_lds = 2 * 32 * 1032 * 2;   // 132096 B
  hipFuncSetAttribute((const void*)kB, hipFuncAttributeMaxDynamicSharedMemorySize, kb_lds);

  kA<<<1152, 256, 0, stream>>>(x1d, norm_w, norm_b, proj_w, proj_b, final_w, Wb, Igp, Jgp);
  kB<<<1024, 512, kb_lds, stream>>>(Igp, Jgp, Wb, final_b, outp);
}

// Round 4
// 139.932 us; speedup vs baseline: 2.9326x; 1.0170x over previous
//
#include <hip/hip_runtime.h>
#include <hip/hip_bf16.h>

#define DEVINL __device__ __forceinline__

typedef float  f32x4_t  __attribute__((ext_vector_type(4)));
typedef float  f32x16_t __attribute__((ext_vector_type(16)));
typedef short  bf16x8_t __attribute__((ext_vector_type(8)));

#define MFMA16(a,b,c) __builtin_amdgcn_mfma_f32_16x16x32_bf16((a),(b),(c),0,0,0)
#define MFMA32(a,b,c) __builtin_amdgcn_mfma_f32_32x32x16_bf16((a),(b),(c),0,0,0)

DEVINL unsigned short f2bf(float f) {
  union { float f; unsigned u; } v; v.f = f;
  unsigned r = v.u + 0x7fffu + ((v.u >> 16) & 1u);   // round-to-nearest-even
  return (unsigned short)(r >> 16);
}

DEVINL unsigned pk2bf(float lo, float hi) {          // bf16(lo) | bf16(hi)<<16, RNE
  union { __hip_bfloat162 h2; unsigned u; } v;
  v.h2 = __float22bfloat162_rn(make_float2(lo, hi));
  return v.u;
}

// ============================ fragment-order layouts ============================
// I/J (bf16): idx = (rowtile*8 + mc)*512 + r32*16 + h*8 + e
//   rowtile = (global row)>>5 (I rows: i_l*32+x; J rows: j_l*32+y), r32 = row&31,
//   m = mc*16 + h*8 + e.  A/B frag for 32x32x16 = 16B at (r32=lane&31, h=lane>>5).
// W (bf16):  idx = (ot*64 + kc)*512 + o32*16 + h*8 + e;  o = ot*32+o32, f = kc*16+h*8+e.

// ---------------- kernel A: LayerNorm + proj + split (+ final_w conversion) ------
__global__ __launch_bounds__(256) void kA(const float* __restrict__ x,
                                          const float* __restrict__ nw,
                                          const float* __restrict__ nb,
                                          const float* __restrict__ pw,
                                          const float* __restrict__ pb,
                                          const float* __restrict__ fw,
                                          unsigned short* __restrict__ Wb,
                                          unsigned short* __restrict__ Ig,
                                          unsigned short* __restrict__ Jg) {
  if (blockIdx.x >= 1024) {                  // final_w fp32 -> bf16, frag order
    int i = (blockIdx.x - 1024) * 256 + threadIdx.x;   // 0..32767
    float4 v = ((const float4*)fw)[i];
    int o  = i >> 8;
    int f0 = (i & 255) * 4;
    ushort4 u;
    u.x = f2bf(v.x); u.y = f2bf(v.y); u.z = f2bf(v.z); u.w = f2bf(v.w);
    size_t off = (size_t)((o >> 5) * 64 + (f0 >> 4)) * 512 + (o & 31) * 16 + ((f0 >> 3) & 1) * 8 + (f0 & 7);
    *(ushort4*)&Wb[off] = u;
    return;
  }
  __shared__ unsigned short xnl[32 * 264];   // 32 m-rows x 256 ch (+8 pad)
  __shared__ unsigned short pwl[64 * 264];   // 64 d x 256 ch (+8 pad)
  __shared__ unsigned short ep[64 * 36];     // transpose buf: [d][m-local]
  const int tid  = threadIdx.x;
  const int wv   = tid >> 6;
  const int lane = tid & 63;
  const int q    = lane >> 4;
  const int ln16 = lane & 15;
  const int l    = blockIdx.x & 255;
  const int m0   = (blockIdx.x >> 8) * 32;

  const float4* xs = (const float4*)x;
  float4 v[8];
#pragma unroll
  for (int i = 0; i < 8; i++) {
    int row = m0 + i * 4 + wv;
    v[i] = xs[row * 16384 + l * 64 + lane];
  }
  float4 nw4 = ((const float4*)nw)[lane];
  float4 nb4 = ((const float4*)nb)[lane];

#pragma unroll
  for (int i = 0; i < 8; i++) {
    float s  = v[i].x + v[i].y + v[i].z + v[i].w;
    float ss = v[i].x * v[i].x + v[i].y * v[i].y + v[i].z * v[i].z + v[i].w * v[i].w;
#pragma unroll
    for (int off = 32; off > 0; off >>= 1) {
      s  += __shfl_xor(s, off);
      ss += __shfl_xor(ss, off);
    }
    float mu  = s * (1.0f / 256.0f);
    float var = ss * (1.0f / 256.0f) - mu * mu;
    float rs  = rsqrtf(var + 1e-5f);
    ushort4 u;
    u.x = f2bf((v[i].x - mu) * rs * nw4.x + nb4.x);
    u.y = f2bf((v[i].y - mu) * rs * nw4.y + nb4.y);
    u.z = f2bf((v[i].z - mu) * rs * nw4.z + nb4.z);
    u.w = f2bf((v[i].w - mu) * rs * nw4.w + nb4.w);
    *(ushort4*)&xnl[(i * 4 + wv) * 264 + lane * 4] = u;
  }

  const float4* ps = (const float4*)pw;
#pragma unroll
  for (int i = 0; i < 16; i++) {
    float4 w4 = ps[i * 256 + tid];
    ushort4 u;
    u.x = f2bf(w4.x); u.y = f2bf(w4.y); u.z = f2bf(w4.z); u.w = f2bf(w4.w);
    *(ushort4*)&pwl[(i * 4 + wv) * 264 + lane * 4] = u;
  }
  __syncthreads();

  const int rt = wv & 1;
  const int db = (wv >> 1) * 32;
  f32x4_t acc[2] = {{0.f, 0.f, 0.f, 0.f}, {0.f, 0.f, 0.f, 0.f}};
#pragma unroll
  for (int kc = 0; kc < 8; kc++) {
    bf16x8_t a  = *(const bf16x8_t*)&xnl[(rt * 16 + ln16) * 264 + kc * 32 + q * 8];
    bf16x8_t b0 = *(const bf16x8_t*)&pwl[(db + ln16) * 264 + kc * 32 + q * 8];
    bf16x8_t b1 = *(const bf16x8_t*)&pwl[(db + 16 + ln16) * 264 + kc * 32 + q * 8];
    acc[0] = MFMA16(a, b0, acc[0]);
    acc[1] = MFMA16(a, b1, acc[1]);
  }

#pragma unroll
  for (int t2 = 0; t2 < 2; t2++) {
    int d = db + t2 * 16 + ln16;
    float bias  = pb[d];
    float scale = (d & 1) ? 1.0f : (1.0f / 128.0f);
#pragma unroll
    for (int r = 0; r < 4; r++) {
      int mloc = rt * 16 + q * 4 + r;
      ep[d * 36 + mloc] = f2bf((acc[t2][r] + bias) * scale);
    }
  }
  __syncthreads();

  // frag-order stores: I from even d (h row = x), J from odd d.
  const int h  = tid >> 3;          // 0..31 (x or y)
  const int m4 = tid & 7;           // m = m0 + m4*4
  const size_t off = (size_t)(l * 8 + (m0 >> 4) + (m4 >> 2)) * 512 + h * 16 + ((m4 >> 1) & 1) * 8 + (m4 & 1) * 4;
  ushort4 vi = *(const ushort4*)&ep[(2 * h) * 36 + m4 * 4];
  *(ushort4*)&Ig[off] = vi;
  ushort4 vj = *(const ushort4*)&ep[(2 * h + 1) * 36 + m4 * 4];
  *(ushort4*)&Jg[off] = vj;
}

// ---------------- kernel B: fused outer-product-mean + final GEMM ----------------
// 2048 blocks x 512 thr; block = (p = i_l pair, t2 = 16-jl tile). fl = 66 KB ->
// 2 blocks/CU (16 waves). GEMM1: P[64 x][512 jy] -> fl rows (il*16+jl) x 1024 f.
// One barrier. GEMM2: 4 o-tiles x 2 K-halves across 8 waves + LDS reduction
// (reuses fl space). W prefetch depth 4, first frags issued pre-barrier.
__global__ __launch_bounds__(512, 4) void kB(const unsigned short* __restrict__ Ig,
                                             const unsigned short* __restrict__ Jg,
                                             const unsigned short* __restrict__ Wb,
                                             const float* __restrict__ fb,
                                             float* __restrict__ out) {
  extern __shared__ unsigned short fl[];     // [32 rows][1032] (pitch pad 8)
  const int tid  = threadIdx.x;
  const int w    = tid >> 6;                 // wave 0..7
  const int lane = tid & 63;
  const int ln32 = lane & 31;
  const int h    = lane >> 5;                // k-octet half
  const int p    = blockIdx.x >> 4;          // i_l pair 0..127
  const int t2   = blockIdx.x & 15;          // 16-jl tile 0..15

  // ---- A-frags (I) for both i_l, held in registers ----
  bf16x8_t af[2][8];
#pragma unroll
  for (int il = 0; il < 2; il++)
#pragma unroll
    for (int mc = 0; mc < 8; mc++)
      af[il][mc] = *(const bf16x8_t*)&Ig[(size_t)((p * 2 + il) * 8 + mc) * 512 + ln32 * 16 + h * 8];

  // ---- GEMM1: wave w covers jl-local rows {w*2, w*2+1} (64 jy), K=128 (m) ----
  const unsigned short* Jbase = Jg + (size_t)(t2 * 16 + w * 2) * 4096 + ln32 * 16 + h * 8;
  const int eo = ln32 & 7;                   // elem within octet
  const int oc = ln32 >> 3;                  // y-octet

  bf16x8_t bf[2][8];
#pragma unroll
  for (int mc = 0; mc < 8; mc++) bf[0][mc] = *(const bf16x8_t*)&Jbase[mc * 512];

#pragma unroll
  for (int s = 0; s < 2; s++) {
    if (s == 0) {
#pragma unroll
      for (int mc = 0; mc < 8; mc++)
        bf[1][mc] = *(const bf16x8_t*)&Jbase[4096 + mc * 512];
    }
    f32x16_t a0, a1;
#pragma unroll
    for (int i = 0; i < 16; i++) { a0[i] = 0.f; a1[i] = 0.f; }
#pragma unroll
    for (int mc = 0; mc < 8; mc++) {
      a0 = MFMA32(af[0][mc], bf[s][mc], a0);
      a1 = MFMA32(af[1][mc], bf[s][mc], a1);
    }
    // write P -> fl rows (il*16 + w*2+s), XOR chunk swizzle c' = (x*4+oc)^(5*((x>>2)&3))
    const int fr = w * 2 + s;
    unsigned short* fr0 = &fl[fr * 1032 + eo];
    unsigned short* fr1 = &fl[(16 + fr) * 1032 + eo];
#pragma unroll
    for (int rp = 0; rp < 8; rp++) {         // reg pairs (2rp, 2rp+1): x, x+1
      int x0  = (2 * rp & 3) + 8 * (rp >> 1) + 4 * h;
      int cp0 = ((x0 * 4 + oc) ^ (((x0 >> 2) & 3) * 5)) * 8;
      int cp1 = (((x0 + 1) * 4 + oc) ^ ((((x0 + 1) >> 2) & 3) * 5)) * 8;
      unsigned u0 = pk2bf(a0[2 * rp], a0[2 * rp + 1]);
      fr0[cp0] = (unsigned short)u0;
      fr0[cp1] = (unsigned short)(u0 >> 16);
      unsigned u1 = pk2bf(a1[2 * rp], a1[2 * rp + 1]);
      fr1[cp0] = (unsigned short)u1;
      fr1[cp1] = (unsigned short)(u1 >> 16);
    }
  }

  // ---- GEMM2 setup: wave -> (ot = w&3 o-tile, kh = w>>2 K-half) ----
  const int ot = w & 3;
  const int kh = w >> 2;
  const unsigned short* Wp = Wb + (size_t)(ot * 64 + kh * 32) * 512 + ln32 * 16 + h * 8;
  bf16x8_t bq[4];
  bq[0] = *(const bf16x8_t*)&Wp[0];          // pre-barrier W prefetch
  bq[1] = *(const bf16x8_t*)&Wp[512];

  __syncthreads();                           // fl ready

  bq[2] = *(const bf16x8_t*)&Wp[2 * 512];
  bq[3] = *(const bf16x8_t*)&Wp[3 * 512];

  const unsigned short* flp = fl + ln32 * 1032;
#define LDA(kc) (*(const bf16x8_t*)&flp[((((kc) >> 1) * 4 + ((kc) & 1) * 2 + h) ^ ((((kc) >> 3) & 3) * 5)) * 8])

  f32x16_t oa;
#pragma unroll
  for (int i = 0; i < 16; i++) oa[i] = 0.f;

  bf16x8_t a0 = LDA(kh * 32), a1 = LDA(kh * 32 + 1);
#pragma unroll
  for (int c = 0; c < 32; c++) {
    bf16x8_t acur = a0;
    bf16x8_t bcur = bq[c & 3];
    if (c < 31) a0 = a1;
    if (c < 30) a1 = LDA(kh * 32 + c + 2);
    if (c < 28) bq[c & 3] = *(const bf16x8_t*)&Wp[(c + 4) * 512];
    oa = MFMA32(acur, bcur, oa);
  }
#undef LDA

  // ---- K-half reduction via LDS (reuse fl space; fl reads all done) ----
  __syncthreads();
  float* red = (float*)fl;                   // 4 tiles x 16 reg x 64 lane = 16 KB
  if (kh == 1) {
#pragma unroll
    for (int r = 0; r < 16; r++) red[(ot * 16 + r) * 64 + lane] = oa[r];
  }
  __syncthreads();
  if (kh == 0) {
    float bias = fb[ot * 32 + ln32];
    float* op = out + ((size_t)(p * 2) * 256 + t2 * 16) * 128 + ot * 32 + ln32;
#pragma unroll
    for (int r = 0; r < 16; r++) {
      float val = oa[r] + red[(ot * 16 + r) * 64 + lane] + bias;
      int row = (r & 3) + 8 * (r >> 2) + 4 * h;   // combined row: il*16 + jl
      op[(row >> 4) * 32768 + (row & 15) * 128] = val;
    }
  }
}

extern "C" void kernel_launch(void* const* d_in, const int* in_sizes, int n_in,
                              void* d_out, int out_size, void* d_ws, size_t ws_size,
                              hipStream_t stream) {
  const float* x1d     = (const float*)d_in[0];
  const float* norm_w  = (const float*)d_in[1];
  const float* norm_b  = (const float*)d_in[2];
  const float* proj_w  = (const float*)d_in[3];
  const float* proj_b  = (const float*)d_in[4];
  const float* final_w = (const float*)d_in[5];
  const float* final_b = (const float*)d_in[6];
  float* outp          = (float*)d_out;

  // workspace carve (bf16): W (128*1024), I (256*32*128), J (256*32*128)
  unsigned short* Wb  = (unsigned short*)d_ws;
  unsigned short* Igp = Wb + 131072;
  unsigned short* Jgp = Igp + 1048576;

  const int kb_lds = 32 * 1032 * 2;   // 66048 B -> 2 blocks/CU
  hipFuncSetAttribute((const void*)kB, hipFuncAttributeMaxDynamicSharedMemorySize, kb_lds);

  kA<<<1152, 256, 0, stream>>>(x1d, norm_w, norm_b, proj_w, proj_b, final_w, Wb, Igp, Jgp);
  kB<<<2048, 512, kb_lds, stream>>>(Igp, Jgp, Wb, final_b, outp);
}

// Round 5
// 136.788 us; speedup vs baseline: 3.0000x; 1.0230x over previous
//
#include <hip/hip_runtime.h>
#include <hip/hip_bf16.h>

#define DEVINL __device__ __forceinline__

typedef float  f32x4_t  __attribute__((ext_vector_type(4)));
typedef float  f32x16_t __attribute__((ext_vector_type(16)));
typedef short  bf16x8_t __attribute__((ext_vector_type(8)));

#define MFMA16(a,b,c) __builtin_amdgcn_mfma_f32_16x16x32_bf16((a),(b),(c),0,0,0)
#define MFMA32(a,b,c) __builtin_amdgcn_mfma_f32_32x32x16_bf16((a),(b),(c),0,0,0)

DEVINL unsigned short f2bf(float f) {
  union { float f; unsigned u; } v; v.f = f;
  unsigned r = v.u + 0x7fffu + ((v.u >> 16) & 1u);   // round-to-nearest-even
  return (unsigned short)(r >> 16);
}

DEVINL unsigned pk2bf(float lo, float hi) {          // bf16(lo) | bf16(hi)<<16, RNE
  union { __hip_bfloat162 h2; unsigned u; } v;
  v.h2 = __float22bfloat162_rn(make_float2(lo, hi));
  return v.u;
}

// ============================ fragment-order layouts ============================
// I/J (bf16): idx = (rowtile*8 + mc)*512 + r32*16 + h*8 + e
//   rowtile = (global row)>>5 (I rows: i_l*32+x; J rows: j_l*32+y), r32 = row&31,
//   m = mc*16 + h*8 + e.  A/B frag for 32x32x16 = 16B at (r32=lane&31, h=lane>>5).
// W (bf16): idx = (oT*64 + kc)*512 + o32*16 + h*8 + e; o = oT*32+o32.
//   K-position kpos = kc*16 + h*8 + e carries f-element with kpos = y*32 + x
//   (f = x*32 + y in the reference) — matches fl's kpos order in kB.

// ---------------- kernel A: LayerNorm + proj + split (+ final_w conversion) ------
__global__ __launch_bounds__(256) void kA(const float* __restrict__ x,
                                          const float* __restrict__ nw,
                                          const float* __restrict__ nb,
                                          const float* __restrict__ pw,
                                          const float* __restrict__ pb,
                                          const float* __restrict__ fw,
                                          unsigned short* __restrict__ Wb,
                                          unsigned short* __restrict__ Ig,
                                          unsigned short* __restrict__ Jg) {
  if (blockIdx.x >= 1024) {                  // final_w fp32 -> bf16, kpos = y*32+x
    int T = (blockIdx.x - 1024) * 256 + threadIdx.x;   // 0..32767
    int o     = T >> 8;
    int kpos0 = (T & 255) * 4;               // 4 consecutive kpos (same y, x-run)
    int y  = kpos0 >> 5;
    int x0 = kpos0 & 31;
    const float* fo = fw + o * 1024 + y;
    ushort4 u;
    u.x = f2bf(fo[(x0 + 0) * 32]);
    u.y = f2bf(fo[(x0 + 1) * 32]);
    u.z = f2bf(fo[(x0 + 2) * 32]);
    u.w = f2bf(fo[(x0 + 3) * 32]);
    size_t off = (size_t)((o >> 5) * 64 + (kpos0 >> 4)) * 512 + (o & 31) * 16
               + ((kpos0 >> 3) & 1) * 8 + (kpos0 & 7);
    *(ushort4*)&Wb[off] = u;
    return;
  }
  __shared__ unsigned short xnl[32 * 264];   // 32 m-rows x 256 ch (+8 pad)
  __shared__ unsigned short pwl[64 * 264];   // 64 d x 256 ch (+8 pad)
  __shared__ unsigned short ep[64 * 36];     // transpose buf: [d][m-local]
  const int tid  = threadIdx.x;
  const int wv   = tid >> 6;
  const int lane = tid & 63;
  const int q    = lane >> 4;
  const int ln16 = lane & 15;
  const int l    = blockIdx.x & 255;
  const int m0   = (blockIdx.x >> 8) * 32;

  const float4* xs = (const float4*)x;
  float4 v[8];
#pragma unroll
  for (int i = 0; i < 8; i++) {
    int row = m0 + i * 4 + wv;
    v[i] = xs[row * 16384 + l * 64 + lane];
  }
  float4 nw4 = ((const float4*)nw)[lane];
  float4 nb4 = ((const float4*)nb)[lane];

#pragma unroll
  for (int i = 0; i < 8; i++) {
    float s  = v[i].x + v[i].y + v[i].z + v[i].w;
    float ss = v[i].x * v[i].x + v[i].y * v[i].y + v[i].z * v[i].z + v[i].w * v[i].w;
#pragma unroll
    for (int off = 32; off > 0; off >>= 1) {
      s  += __shfl_xor(s, off);
      ss += __shfl_xor(ss, off);
    }
    float mu  = s * (1.0f / 256.0f);
    float var = ss * (1.0f / 256.0f) - mu * mu;
    float rs  = rsqrtf(var + 1e-5f);
    ushort4 u;
    u.x = f2bf((v[i].x - mu) * rs * nw4.x + nb4.x);
    u.y = f2bf((v[i].y - mu) * rs * nw4.y + nb4.y);
    u.z = f2bf((v[i].z - mu) * rs * nw4.z + nb4.z);
    u.w = f2bf((v[i].w - mu) * rs * nw4.w + nb4.w);
    *(ushort4*)&xnl[(i * 4 + wv) * 264 + lane * 4] = u;
  }

  const float4* ps = (const float4*)pw;
#pragma unroll
  for (int i = 0; i < 16; i++) {
    float4 w4 = ps[i * 256 + tid];
    ushort4 u;
    u.x = f2bf(w4.x); u.y = f2bf(w4.y); u.z = f2bf(w4.z); u.w = f2bf(w4.w);
    *(ushort4*)&pwl[(i * 4 + wv) * 264 + lane * 4] = u;
  }
  __syncthreads();

  const int rt = wv & 1;
  const int db = (wv >> 1) * 32;
  f32x4_t acc[2] = {{0.f, 0.f, 0.f, 0.f}, {0.f, 0.f, 0.f, 0.f}};
#pragma unroll
  for (int kc = 0; kc < 8; kc++) {
    bf16x8_t a  = *(const bf16x8_t*)&xnl[(rt * 16 + ln16) * 264 + kc * 32 + q * 8];
    bf16x8_t b0 = *(const bf16x8_t*)&pwl[(db + ln16) * 264 + kc * 32 + q * 8];
    bf16x8_t b1 = *(const bf16x8_t*)&pwl[(db + 16 + ln16) * 264 + kc * 32 + q * 8];
    acc[0] = MFMA16(a, b0, acc[0]);
    acc[1] = MFMA16(a, b1, acc[1]);
  }

#pragma unroll
  for (int t2 = 0; t2 < 2; t2++) {
    int d = db + t2 * 16 + ln16;
    float bias  = pb[d];
    float scale = (d & 1) ? 1.0f : (1.0f / 128.0f);
#pragma unroll
    for (int r = 0; r < 4; r++) {
      int mloc = rt * 16 + q * 4 + r;
      ep[d * 36 + mloc] = f2bf((acc[t2][r] + bias) * scale);
    }
  }
  __syncthreads();

  // frag-order stores: I from even d (h row = x), J from odd d.
  const int h  = tid >> 3;          // 0..31 (x or y)
  const int m4 = tid & 7;           // m = m0 + m4*4
  const size_t off = (size_t)(l * 8 + (m0 >> 4) + (m4 >> 2)) * 512 + h * 16 + ((m4 >> 1) & 1) * 8 + (m4 & 1) * 4;
  ushort4 vi = *(const ushort4*)&ep[(2 * h) * 36 + m4 * 4];
  *(ushort4*)&Ig[off] = vi;
  ushort4 vj = *(const ushort4*)&ep[(2 * h + 1) * 36 + m4 * 4];
  *(ushort4*)&Jg[off] = vj;
}

// ---------------- kernel B: fused outer-product-mean + final GEMM ----------------
// 1024 blocks x 512 thr; block = (p: 4 i_l) x (t: 16 j_l) -> 64 output rows.
// fl[64 rows][1048] bf16 (131 KB, 1 block/CU). kpos = y*32+x; 16B chunks XOR-
// swizzled c ^= (c>>2)&7 (bank-balanced for b64 writes and b128 reads).
// GEMM1: J/I frags direct from L2/L1, b64 epilogue writes. One main barrier.
// GEMM2: W partitioned per wave (ot x kh), depth-4 ring started pre-barrier;
// K-half reduction via fp32 scratch reusing fl.
__global__ __launch_bounds__(512, 2) void kB(const unsigned short* __restrict__ Ig,
                                             const unsigned short* __restrict__ Jg,
                                             const unsigned short* __restrict__ Wb,
                                             const float* __restrict__ fb,
                                             float* __restrict__ out) {
  extern __shared__ unsigned short fl[];     // 64 x 1048
  constexpr int P = 1048;
  const int tid  = threadIdx.x;
  const int w    = tid >> 6;                 // wave 0..7
  const int lane = tid & 63;
  const int ln32 = lane & 31;
  const int h    = lane >> 5;
  const int p    = blockIdx.x >> 4;          // i_l quad 0..63
  const int t    = blockIdx.x & 15;          // j_l tile-of-16 0..15

  // ---------- GEMM1: wave w -> jl in {2w, 2w+1}; all 4 il ----------
  bf16x8_t jb[2][8];
  const size_t jbase = (size_t)(t * 16 + 2 * w) * 4096 + ln32 * 16 + h * 8;
#pragma unroll
  for (int mc = 0; mc < 8; mc++) jb[0][mc] = *(const bf16x8_t*)&Jg[jbase + mc * 512];
#pragma unroll
  for (int mc = 0; mc < 8; mc++) jb[1][mc] = *(const bf16x8_t*)&Jg[jbase + 4096 + mc * 512];

#pragma unroll
  for (int s = 0; s < 2; s++) {
    const int jl = 2 * w + s;
#pragma unroll
    for (int ilp = 0; ilp < 2; ilp++) {
      bf16x8_t af[2][8];
#pragma unroll
      for (int u = 0; u < 2; u++)
#pragma unroll
        for (int mc = 0; mc < 8; mc++)
          af[u][mc] = *(const bf16x8_t*)&Ig[(size_t)((p * 4 + ilp * 2 + u) * 8 + mc) * 512 + ln32 * 16 + h * 8];
      f32x16_t c[2];
#pragma unroll
      for (int i = 0; i < 16; i++) { c[0][i] = 0.f; c[1][i] = 0.f; }
#pragma unroll
      for (int mc = 0; mc < 8; mc++) {
        c[0] = MFMA32(af[0][mc], jb[s][mc], c[0]);
        c[1] = MFMA32(af[1][mc], jb[s][mc], c[1]);
      }
      // lane: col y = ln32; reg quad g covers x = 8g + 4h .. +3 -> one b64 each
#pragma unroll
      for (int u = 0; u < 2; u++) {
        unsigned short* fr = &fl[((ilp * 2 + u) * 16 + jl) * P];
#pragma unroll
        for (int g = 0; g < 4; g++) {
          int cp = (4 * ln32 + g) ^ (ln32 & 7);
          uint2 pv;
          pv.x = pk2bf(c[u][4 * g + 0], c[u][4 * g + 1]);
          pv.y = pk2bf(c[u][4 * g + 2], c[u][4 * g + 3]);
          *(uint2*)&fr[cp * 8 + h * 4] = pv;
        }
      }
    }
  }

  // ---------- GEMM2: wave -> (ot = w&3: 32 o, kh = w>>2: K-half 512) ----------
  const int ot = w & 3;
  const int kh = w >> 2;
  const unsigned short* Wp = Wb + (size_t)(ot * 64 + kh * 32) * 512 + ln32 * 16 + h * 8;
  bf16x8_t bq[4];
  bq[0] = *(const bf16x8_t*)&Wp[0];          // pre-barrier W prefetch
  bq[1] = *(const bf16x8_t*)&Wp[512];

  __syncthreads();                           // fl ready

  bq[2] = *(const bf16x8_t*)&Wp[2 * 512];
  bq[3] = *(const bf16x8_t*)&Wp[3 * 512];

  // A-frag: row = rt*32 + ln32; chunk c = (kh*32+kc)*2 + h, swizzled
#define LDA(rt, kc) (*(const bf16x8_t*)&fl[((rt) * 32 + ln32) * P + \
    ((((kh * 32 + (kc)) * 2 + h) ^ (((kh * 32 + (kc)) >> 1) & 7)) * 8)])

  f32x16_t o2[2];
#pragma unroll
  for (int i = 0; i < 16; i++) { o2[0][i] = 0.f; o2[1][i] = 0.f; }

  bf16x8_t a0 = LDA(0, 0), a1 = LDA(1, 0);
#pragma unroll
  for (int kc = 0; kc < 32; kc++) {
    bf16x8_t ac0 = a0, ac1 = a1, bc = bq[kc & 3];
    if (kc < 31) { a0 = LDA(0, kc + 1); a1 = LDA(1, kc + 1); }
    if (kc < 28) bq[kc & 3] = *(const bf16x8_t*)&Wp[(kc + 4) * 512];
    o2[0] = MFMA32(ac0, bc, o2[0]);
    o2[1] = MFMA32(ac1, bc, o2[1]);
  }
#undef LDA

  // ---------- K-half reduction via fp32 scratch in fl ----------
  __syncthreads();                           // all fl reads done
  float* red = (float*)fl;                   // 8 tiles x 1024 f32 = 32 KB
  if (kh == 1) {
#pragma unroll
    for (int rt = 0; rt < 2; rt++) {
      float* bb = red + (ot * 2 + rt) * 1024 + lane * 2;
#pragma unroll
      for (int k = 0; k < 8; k++)
        *(float2*)&bb[k * 128] = make_float2(o2[rt][2 * k], o2[rt][2 * k + 1]);
    }
  }
  __syncthreads();
  if (kh == 0) {
    const float bias = fb[ot * 32 + ln32];
    float* ob = out + ((size_t)(p * 4) * 256 + t * 16) * 128 + ot * 32 + ln32;
#pragma unroll
    for (int rt = 0; rt < 2; rt++) {
      const float* bb = red + (ot * 2 + rt) * 1024 + lane * 2;
#pragma unroll
      for (int k = 0; k < 8; k++) {
        float2 rv = *(const float2*)&bb[k * 128];
        int r0 = 2 * k, r1 = 2 * k + 1;
        int br0 = rt * 32 + (r0 & 3) + 8 * (r0 >> 2) + 4 * h;
        int br1 = rt * 32 + (r1 & 3) + 8 * (r1 >> 2) + 4 * h;
        ob[(br0 >> 4) * 32768 + (br0 & 15) * 128] = o2[rt][r0] + rv.x + bias;
        ob[(br1 >> 4) * 32768 + (br1 & 15) * 128] = o2[rt][r1] + rv.y + bias;
      }
    }
  }
}

extern "C" void kernel_launch(void* const* d_in, const int* in_sizes, int n_in,
                              void* d_out, int out_size, void* d_ws, size_t ws_size,
                              hipStream_t stream) {
  const float* x1d     = (const float*)d_in[0];
  const float* norm_w  = (const float*)d_in[1];
  const float* norm_b  = (const float*)d_in[2];
  const float* proj_w  = (const float*)d_in[3];
  const float* proj_b  = (const float*)d_in[4];
  const float* final_w = (const float*)d_in[5];
  const float* final_b = (const float*)d_in[6];
  float* outp          = (float*)d_out;

  // workspace carve (bf16): W (128*1024), I (256*32*128), J (256*32*128)
  unsigned short* Wb  = (unsigned short*)d_ws;
  unsigned short* Igp = Wb + 131072;
  unsigned short* Jgp = Igp + 1048576;

  const int kb_lds = 64 * 1048 * 2;   // 134144 B -> 1 block/CU
  hipFuncSetAttribute((const void*)kB, hipFuncAttributeMaxDynamicSharedMemorySize, kb_lds);

  kA<<<1152, 256, 0, stream>>>(x1d, norm_w, norm_b, proj_w, proj_b, final_w, Wb, Igp, Jgp);
  kB<<<1024, 512, kb_lds, stream>>>(Igp, Jgp, Wb, final_b, outp);
}